// Round 7
// baseline (235.487 us; speedup 1.0000x reference)
//
#include <hip/hip_runtime.h>
#include <stdint.h>

#define SX 2048
#define SYY 2048
#define DDIM 1024
#define NBATCH 8

typedef _Float16 f16;
typedef __attribute__((ext_vector_type(2))) _Float16 h2_t;
typedef __attribute__((ext_vector_type(4))) _Float16 h4_t;
typedef __attribute__((ext_vector_type(8))) _Float16 h8_t;
typedef __attribute__((ext_vector_type(4))) float fx4_t;

__device__ __forceinline__ void gload_lds16(const void* g, void* l) {
  __builtin_amdgcn_global_load_lds((const __attribute__((address_space(1))) void*)g,
                                   (__attribute__((address_space(3))) void*)l,
                                   16, 0, 0);
}

// ---- prep: copy x into out[:, :, 0:D] (fp32) AND convert x -> fp16 ----
__global__ __launch_bounds__(256) void k_prep_x(const float4* __restrict__ x,
                                                float* __restrict__ out,
                                                h4_t* __restrict__ x16, long n4) {
  long i = (long)blockIdx.x * blockDim.x + threadIdx.x;
  long stride = (long)gridDim.x * blockDim.x;
  for (; i < n4; i += stride) {
    long bi = i >> 8;            // / (DDIM/4)
    int dq = (int)(i & 255);
    float4 v = x[i];
    *(float4*)(out + bi * (2 * DDIM) + dq * 4) = v;
    h4_t h = { (f16)v.x, (f16)v.y, (f16)v.z, (f16)v.w };
    x16[i] = h;
  }
}

// ---- y[z][j][d] fp32 -> Y16[z][j][d] fp16 and Yt16[z][d][j] fp16 ----
__global__ __launch_bounds__(256) void k_trans(const float* __restrict__ y,
                                               f16* __restrict__ y16,
                                               f16* __restrict__ yt16) {
  __shared__ f16 tile[64][72];
  int z = blockIdx.z;
  int d0 = blockIdx.x * 64, j0 = blockIdx.y * 64;
  const float* yb = y + (size_t)z * SYY * DDIM;
  f16* y16b = y16 + (size_t)z * SYY * DDIM;
  f16* ytb = yt16 + (size_t)z * DDIM * SYY;
  int t = threadIdx.x;
  int jl = t >> 2;
  int dq = t & 3;
#pragma unroll
  for (int s = 0; s < 4; ++s) {
    int dl = dq * 16 + s * 4;
    float4 v = *(const float4*)(yb + (size_t)(j0 + jl) * DDIM + d0 + dl);
    h4_t h = { (f16)v.x, (f16)v.y, (f16)v.z, (f16)v.w };
    *(h4_t*)(y16b + (size_t)(j0 + jl) * DDIM + d0 + dl) = h;
    *(h4_t*)&tile[jl][dl] = h;
  }
  __syncthreads();
  int dl2 = t >> 2;
  int jq = t & 3;
  f16 vbuf[16] __attribute__((aligned(16)));
#pragma unroll
  for (int u = 0; u < 16; ++u) vbuf[u] = tile[jq * 16 + u][dl2];
  f16* orow = ytb + (size_t)(d0 + dl2) * SYY + j0 + jq * 16;
  *(uint4*)orow = *(const uint4*)&vbuf[0];
  *(uint4*)(orow + 8) = *(const uint4*)&vbuf[8];
}

// ==== shared 256x256 8-phase GEMM machinery (round-3 verified ledger) ====
#define PH_BAR() __builtin_amdgcn_s_barrier()

#define STAGE_A(AR, SLOT, HALF, T) {                                           \
    const f16* s_ = (AR) + (size_t)((HALF) * 64) * lda + (T) * 64;             \
    f16* d_ = lds + (SLOT) * 8192 + dstoff;                                    \
    gload_lds16(s_, d_);                                                       \
    gload_lds16(s_ + (size_t)128 * lda, d_ + 4096); }

#define STAGE_B(BR, SLOT, HALF, T) {                                           \
    const f16* s_ = (BR) + (size_t)((HALF) * 32) * ldb + (T) * 64;             \
    f16* d_ = lds + (SLOT) * 8192 + dstoff;                                    \
    gload_lds16(s_, d_);                                                       \
    gload_lds16(s_ + (size_t)128 * ldb, d_ + 4096); }

#define RD_A(PTR, CB) { _Pragma("unroll") for (int i_ = 0; i_ < 4; ++i_) {     \
    af[i_][0] = *(const h8_t*)((PTR) + (CB) + i_ * 2048 + kb0);                \
    af[i_][1] = *(const h8_t*)((PTR) + (CB) + i_ * 2048 + kb1); } }

// gemm2 variant: scale A-fragments by per-row factor fdc[MOFF + i]
#define RD_A_S(PTR, CB, MOFF) { _Pragma("unroll") for (int i_ = 0; i_ < 4; ++i_) { \
    h8_t a0 = *(const h8_t*)((PTR) + (CB) + i_ * 2048 + kb0);                  \
    h8_t a1 = *(const h8_t*)((PTR) + (CB) + i_ * 2048 + kb1);                  \
    h2_t* p0 = (h2_t*)&a0; h2_t* p1 = (h2_t*)&a1;                              \
    _Pragma("unroll") for (int q_ = 0; q_ < 4; ++q_) {                         \
      p0[q_] *= fdc[(MOFF) + i_]; p1[q_] *= fdc[(MOFF) + i_]; }                \
    af[i_][0] = a0; af[i_][1] = a1; } }

#define RD_B(PTR, CB, NH) { _Pragma("unroll") for (int j_ = 0; j_ < 2; ++j_) { \
    bf[(NH) + j_][0] = *(const h8_t*)((PTR) + (CB) + j_ * 2048 + kb0);         \
    bf[(NH) + j_][1] = *(const h8_t*)((PTR) + (CB) + j_ * 2048 + kb1); } }

#define MM(MH, NH) { __builtin_amdgcn_s_setprio(1);                            \
  _Pragma("unroll") for (int i_ = 0; i_ < 4; ++i_)                             \
  _Pragma("unroll") for (int j_ = 0; j_ < 2; ++j_) {                           \
    acc[(MH) + i_][(NH) + j_] = __builtin_amdgcn_mfma_f32_16x16x32_f16(        \
        af[i_][0], bf[(NH) + j_][0], acc[(MH) + i_][(NH) + j_], 0, 0, 0);      \
    acc[(MH) + i_][(NH) + j_] = __builtin_amdgcn_mfma_f32_16x16x32_f16(        \
        af[i_][1], bf[(NH) + j_][1], acc[(MH) + i_][(NH) + j_], 0, 0, 0); }    \
  __builtin_amdgcn_s_setprio(0); }

#define GEMM_COMMON_SETUP()                                                    \
  const int tid = threadIdx.x;                                                 \
  const int lane = tid & 63, w = tid >> 6;                                     \
  const int wr = w >> 2, wc = w & 3;                                           \
  const int fr = lane & 15, fh = lane >> 4;                                    \
  const int l0 = 8 * w + (lane >> 3);                                          \
  const int r0b = ((l0 >> 5) << 6) | (l0 & 31);                                \
  const int swz = 8 * ((lane & 7) ^ (lane >> 3));                              \
  const int dstoff = w * 512 + lane * 8;                                       \
  const char* ldsAlo = (const char*)lds + wr * 8192 + fr * 128;                \
  const char* ldsAhi = ldsAlo + 16384;                                         \
  const char* ldsBlo = (const char*)lds + 32768 + wc * 4096 + fr * 128;        \
  const char* ldsBhi = ldsBlo + 16384;                                         \
  const int kb0 = ((0 + fh) ^ (fr & 7)) * 16;                                  \
  const int kb1 = ((4 + fh) ^ (fr & 7)) * 16;

// logical-id -> (z, m0, n0) with n-major half-m ordering for L2 reuse
#define COMPUTE_TILE(IDX, AR, BR, ZV, M0V, N0V) {                              \
    int id_ = (IDX);                                                           \
    ZV = id_ / tpz; int rem_ = id_ - ZV * tpz;                                 \
    int mt_, ntl_;                                                             \
    if ((ntm & 1) == 0) {                                                      \
      int ht_ = tpz >> 1, hm_ = ntm >> 1;                                      \
      int half_ = rem_ / ht_, j_ = rem_ - half_ * ht_;                         \
      ntl_ = j_ / hm_; mt_ = half_ * hm_ + (j_ - ntl_ * hm_);                  \
    } else { mt_ = rem_ / ntn; ntl_ = rem_ - mt_ * ntn; }                      \
    M0V = mt_ * 256; N0V = ntl_ * 256;                                         \
    AR = A + (size_t)ZV * a_zs + (size_t)(a_row0 + M0V) * lda                  \
           + (size_t)l0 * lda + swz;                                           \
    BR = B + (size_t)ZV * b_zs + (size_t)N0V * ldb                             \
           + (size_t)r0b * ldb + swz; }

// ==== GEMM1 (persistent, tpb tiles/block): S = X.Y^T + fused softmax epi ====
__global__ __launch_bounds__(512, 2) void k_gemm1(
    const f16* __restrict__ A, long a_zs, int a_row0, int lda,
    const f16* __restrict__ B, long b_zs, int ldb,
    f16* __restrict__ U, long u_zs,
    float2* __restrict__ ML, int mrows,
    int K, int ntm, int ntn, int nblk, int tpb)
{
  __shared__ f16 lds[69632];   // 128 KiB ring + 8 KiB epilogue scratch
  GEMM_COMMON_SETUP();
  const int tpz = ntm * ntn;
  const int nt = K >> 6;
  const int ng = nt >> 1;
  const int nphys = nblk / tpb;
  const int nper = nblk >> 3, bper = nphys >> 3;
  const int xcd = blockIdx.x & 7, lb = blockIdx.x >> 3;
  const bool chunk8 = ((nblk & 7) == 0) && ((nphys & 7) == 0);

  const f16 *aRowC, *bRowC, *aRowN = A, *bRowN = B;
  int zC, m0C, n0C, zN = 0, m0N = 0, n0N = 0;
  int id0 = chunk8 ? (xcd * nper + lb) : (int)blockIdx.x;
  int idstep = chunk8 ? bper : nphys;
  COMPUTE_TILE(id0, aRowC, bRowC, zC, m0C, n0C);
  if (tpb > 1) COMPUTE_TILE(id0 + idstep, aRowN, bRowN, zN, m0N, n0N);

  fx4_t acc[8][4];
#pragma unroll
  for (int i = 0; i < 8; ++i)
#pragma unroll
    for (int j = 0; j < 4; ++j) { fx4_t zv = {0.f,0.f,0.f,0.f}; acc[i][j] = zv; }
  h8_t af[4][2], bf[4][2];

  // prologue: tile0 of first tile -> slots 0,1,2,3 ; ktile1 -> slots 4,6,7
  STAGE_A(aRowC, 0, 0, 0); STAGE_A(aRowC, 1, 1, 0);
  STAGE_B(bRowC, 2, 0, 0); STAGE_B(bRowC, 3, 1, 0);
  STAGE_A(aRowC, 4, 0, 1); STAGE_B(bRowC, 6, 0, 1); STAGE_B(bRowC, 7, 1, 1);
  asm volatile("s_waitcnt vmcnt(6)" ::: "memory");
  PH_BAR();

  const int GG = ng * tpb, KT = nt * tpb;
  int tl = 0;
  for (int gg = 0; gg < GG; ++gg) {
    const int gloc = gg - tl * ng;
    const int T1 = 2 * gloc + 1;
    const int kt2 = 2 * gg + 2, kt3 = 2 * gg + 3;
    const bool h2 = kt2 < KT, h3 = kt3 < KT;
    const int tb = (tl + 1) * nt;
    const bool n2 = kt2 >= tb, n3 = kt3 >= tb;
    const f16* a2 = n2 ? aRowN : aRowC; const f16* b2 = n2 ? bRowN : bRowC;
    const f16* a3 = n3 ? aRowN : aRowC; const f16* b3 = n3 ? bRowN : bRowC;
    const int T2 = kt2 - (n2 ? tb : tl * nt);
    const int T3 = kt3 - (n3 ? tb : tl * nt);
    // ph0
    RD_A(ldsAlo, 0); RD_B(ldsBlo, 0, 0);
    STAGE_A(aRowC, 5, 1, T1);
    PH_BAR(); MM(0, 0); PH_BAR();
    // ph1
    RD_B(ldsBhi, 0, 2);
    if (h2) STAGE_A(a2, 0, 0, T2);
    PH_BAR(); MM(0, 2); PH_BAR();
    // ph2
    RD_A(ldsAhi, 0);
    if (h2) STAGE_B(b2, 2, 0, T2);
    PH_BAR(); MM(4, 0); PH_BAR();
    // ph3
    if (h2) STAGE_B(b2, 3, 1, T2);
    PH_BAR(); MM(4, 2);
    if (h2) { asm volatile("s_waitcnt vmcnt(6)" ::: "memory"); }
    else    { asm volatile("s_waitcnt vmcnt(0)" ::: "memory"); }
    PH_BAR();
    // ph4
    RD_A(ldsAlo, 65536); RD_B(ldsBlo, 65536, 0);
    if (h2) STAGE_A(a2, 1, 1, T2);
    PH_BAR(); MM(0, 0); PH_BAR();
    // ph5
    RD_B(ldsBhi, 65536, 2);
    if (h3) STAGE_A(a3, 4, 0, T3);
    PH_BAR(); MM(0, 2); PH_BAR();
    // ph6
    RD_A(ldsAhi, 65536);
    if (h3) STAGE_B(b3, 6, 0, T3);
    PH_BAR(); MM(4, 0); PH_BAR();
    // ph7
    if (h3) STAGE_B(b3, 7, 1, T3);
    PH_BAR(); MM(4, 2);
    if (h2) { asm volatile("s_waitcnt vmcnt(6)" ::: "memory"); }
    else    { asm volatile("s_waitcnt vmcnt(0)" ::: "memory"); }
    PH_BAR();

    if (gloc == ng - 1) {
      // ---- slim fused-softmax epilogue for tile (zC, m0C, n0C) ----
      float2* mlx = (float2*)(lds + 65536);
      const int rbase = wr * 128 + fh * 4;
      float mw[8][4];
#pragma unroll
      for (int mi = 0; mi < 8; ++mi)
#pragma unroll
        for (int rr = 0; rr < 4; ++rr) {
          float am = fmaxf(fmaxf(acc[mi][0][rr], acc[mi][1][rr]),
                           fmaxf(acc[mi][2][rr], acc[mi][3][rr]));
          am = fmaxf(am, __shfl_xor(am, 1)); am = fmaxf(am, __shfl_xor(am, 2));
          am = fmaxf(am, __shfl_xor(am, 4)); am = fmaxf(am, __shfl_xor(am, 8));
          float s = 0.f;
#pragma unroll
          for (int ni = 0; ni < 4; ++ni) {
            float e = __expf(acc[mi][ni][rr] - am);
            acc[mi][ni][rr] = e; s += e;
          }
          s += __shfl_xor(s, 1); s += __shfl_xor(s, 2);
          s += __shfl_xor(s, 4); s += __shfl_xor(s, 8);
          mw[mi][rr] = am;
          if (fr == 0) {
            float2 v; v.x = am; v.y = s;
            mlx[(rbase + mi * 16 + rr) * 4 + wc] = v;
          }
        }
      asm volatile("s_waitcnt lgkmcnt(0)" ::: "memory");
      PH_BAR();
      f16* Ub = U + (size_t)zC * u_zs;
      float2* MLp = ML + ((size_t)zC * 8 + (n0C >> 8)) * mrows + m0C;
#pragma unroll
      for (int mi = 0; mi < 8; ++mi)
#pragma unroll
        for (int rr = 0; rr < 4; ++rr) {
          int row = rbase + mi * 16 + rr;
          float4 p01 = *(float4*)&mlx[row * 4 + 0];
          float4 p23 = *(float4*)&mlx[row * 4 + 2];
          float mt = fmaxf(fmaxf(p01.x, p01.z), fmaxf(p23.x, p23.z));
          float lt = p01.y * __expf(p01.x - mt) + p01.w * __expf(p01.z - mt) +
                     p23.y * __expf(p23.x - mt) + p23.w * __expf(p23.z - mt);
          float sc = __expf(mw[mi][rr] - mt);
#pragma unroll
          for (int ni = 0; ni < 4; ++ni)
            Ub[(size_t)(m0C + row) * SYY + n0C + wc * 64 + ni * 16 + fr] =
                (f16)(acc[mi][ni][rr] * sc);
          if (wc == 0 && fr == 0) { float2 v; v.x = mt; v.y = lt; MLp[row] = v; }
        }
      // rotate to next tile
      aRowC = aRowN; bRowC = bRowN; zC = zN; m0C = m0N; n0C = n0N;
      ++tl;
#pragma unroll
      for (int i = 0; i < 8; ++i)
#pragma unroll
        for (int j = 0; j < 4; ++j) { fx4_t zv = {0.f,0.f,0.f,0.f}; acc[i][j] = zv; }
    }
  }
}

// ---- per-row combine: 8 tiles' (m,l) -> factor_t = exp(m_t - M)/L (f16) ----
__global__ __launch_bounds__(256) void k_mlred(const float2* __restrict__ ML,
                                               f16* __restrict__ Fq,
                                               int rows, long total) {
  long idx = (long)blockIdx.x * blockDim.x + threadIdx.x;
  if (idx >= total) return;
  int z = (int)(idx / rows);
  int r = (int)(idx - (long)z * rows);
  float2 v[8];
  float M = -3.4e38f;
#pragma unroll
  for (int t = 0; t < 8; ++t) {
    v[t] = ML[((size_t)z * 8 + t) * rows + r];
    M = fmaxf(M, v[t].x);
  }
  float L = 0.f;
#pragma unroll
  for (int t = 0; t < 8; ++t) L += v[t].y * __expf(v[t].x - M);
  float inv = 1.0f / L;
#pragma unroll
  for (int t = 0; t < 8; ++t)
    Fq[((size_t)z * 8 + t) * rows + r] = (f16)(__expf(v[t].x - M) * inv);
}

// ==== GEMM2: out_right = (u * factor) . Yt^T, factor applied on A-frags ====
__global__ __launch_bounds__(512, 2) void k_gemm2(
    const f16* __restrict__ A, long a_zs, int a_row0, int lda,
    const f16* __restrict__ B, long b_zs, int ldb,
    float* __restrict__ C, long c_zs, int c_row0, int ldc, int c_col0,
    const f16* __restrict__ Fq, int mrows,
    int K, int ntm, int ntn, int nblk)
{
  __shared__ f16 lds[65536];
  GEMM_COMMON_SETUP();
  const int tpz = ntm * ntn;
  int bid = blockIdx.x;
  int id = bid;
  if ((nblk & 7) == 0) { int cpx = nblk >> 3; id = (bid & 7) * cpx + (bid >> 3); }
  const f16 *aRow, *bRow;
  int z, m0, n0;
  COMPUTE_TILE(id, aRow, bRow, z, m0, n0);

  const int nt = K >> 6;
  const int ng = nt >> 1;

  fx4_t acc[8][4];
#pragma unroll
  for (int i = 0; i < 8; ++i)
#pragma unroll
    for (int j = 0; j < 4; ++j) { fx4_t zv = {0.f,0.f,0.f,0.f}; acc[i][j] = zv; }
  h8_t af[4][2], bf[4][2];

  // factor base: row(mi) = m0 + wr*128 + mi*16 + fr, table [z][t][mrows]
  const f16* Fb = Fq + (size_t)z * 8 * mrows + m0 + wr * 128 + fr;
  h2_t fdc[8], fdn[8];
#pragma unroll
  for (int i = 0; i < 8; ++i) {
    f16 fv = Fb[i * 16];
    h2_t d; d[0] = fv; d[1] = fv; fdn[i] = d;
  }

  STAGE_A(aRow, 0, 0, 0); STAGE_A(aRow, 1, 1, 0);
  STAGE_B(bRow, 2, 0, 0); STAGE_B(bRow, 3, 1, 0);
  STAGE_A(aRow, 4, 0, 1); STAGE_B(bRow, 6, 0, 1); STAGE_B(bRow, 7, 1, 1);
  asm volatile("s_waitcnt vmcnt(6)" ::: "memory");
  PH_BAR();

  for (int g = 0; g < ng; ++g) {
    const int T1 = 2 * g + 1, T2 = 2 * g + 2, T3 = 2 * g + 3;
    const bool nl = (g < ng - 1);
    const bool ev = ((g & 1) == 0);
    if (ev) {
#pragma unroll
      for (int i = 0; i < 8; ++i) fdc[i] = fdn[i];
    }
    RD_A_S(ldsAlo, 0, 0); RD_B(ldsBlo, 0, 0);
    STAGE_A(aRow, 5, 1, T1);
    PH_BAR(); MM(0, 0); PH_BAR();
    RD_B(ldsBhi, 0, 2);
    if (nl) STAGE_A(aRow, 0, 0, T2);
    PH_BAR(); MM(0, 2); PH_BAR();
    RD_A_S(ldsAhi, 0, 4);
    if (nl) STAGE_B(bRow, 2, 0, T2);
    PH_BAR(); MM(4, 0); PH_BAR();
    if (nl) STAGE_B(bRow, 3, 1, T2);
    PH_BAR(); MM(4, 2);
    if (nl) { asm volatile("s_waitcnt vmcnt(6)" ::: "memory"); }
    else    { asm volatile("s_waitcnt vmcnt(0)" ::: "memory"); }
    PH_BAR();
    // ph4: factor prefetch AFTER the checkpoint (keeps stage FIFO ledger exact)
    RD_A_S(ldsAlo, 65536, 0); RD_B(ldsBlo, 65536, 0);
    if (ev) {
      int tn = (g >> 1) + 1;
      if (tn < 8) {
        const f16* Fn = Fb + (size_t)tn * mrows;
#pragma unroll
        for (int i = 0; i < 8; ++i) {
          f16 fv = Fn[i * 16];
          h2_t d; d[0] = fv; d[1] = fv; fdn[i] = d;
        }
      }
    }
    if (nl) STAGE_A(aRow, 1, 1, T2);
    PH_BAR(); MM(0, 0); PH_BAR();
    RD_B(ldsBhi, 65536, 2);
    if (nl) STAGE_A(aRow, 4, 0, T3);
    PH_BAR(); MM(0, 2); PH_BAR();
    RD_A_S(ldsAhi, 65536, 4);
    if (nl) STAGE_B(bRow, 6, 0, T3);
    PH_BAR(); MM(4, 0); PH_BAR();
    if (nl) STAGE_B(bRow, 7, 1, T3);
    PH_BAR(); MM(4, 2);
    asm volatile("s_waitcnt vmcnt(6)" ::: "memory");
    PH_BAR();
  }

  float* Cb = C + (size_t)z * c_zs +
              (size_t)(c_row0 + m0 + wr * 128) * ldc + c_col0 + n0 + wc * 64;
#pragma unroll
  for (int mi = 0; mi < 8; ++mi)
#pragma unroll
    for (int ni = 0; ni < 4; ++ni)
#pragma unroll
      for (int r = 0; r < 4; ++r)
        Cb[(size_t)(mi * 16 + fh * 4 + r) * ldc + ni * 16 + fr] = acc[mi][ni][r];
}

extern "C" void kernel_launch(void* const* d_in, const int* in_sizes, int n_in,
                              void* d_out, int out_size, void* d_ws, size_t ws_size,
                              hipStream_t stream) {
  (void)in_sizes; (void)n_in; (void)out_size;
  const float* x = (const float*)d_in[0];
  const float* y = (const float*)d_in[1];
  float* out = (float*)d_out;

  // ws layout per group: U(f16) | ML(float2 x8) | Fq(f16 x8) | X16 | Y16 | Yt16
  size_t per_batch = (size_t)SX * SYY * 2 + (size_t)8 * SX * 8 + (size_t)8 * SX * 2 +
                     (size_t)SX * DDIM * 2 + (size_t)SYY * DDIM * 2 +
                     (size_t)DDIM * SYY * 2;
  int nb = (int)(ws_size / per_batch);
  if (nb > NBATCH) nb = NBATCH;
  int CH = SX;
  if (nb < 1) {
    nb = 1;
    size_t conv = (size_t)SX * DDIM * 2 + (size_t)SYY * DDIM * 2 +
                  (size_t)DDIM * SYY * 2;
    size_t avail = ws_size > conv ? ws_size - conv : 0;
    long ch = (long)(avail / ((size_t)SYY * 2 + 80));
    ch = (ch / 256) * 256;
    if (ch < 256) ch = 256;
    if (ch > SX) ch = SX;
    CH = (int)ch;
  }

  char* w = (char*)d_ws;
  f16* Ubuf = (f16*)w;            size_t off = (size_t)nb * CH * SYY * 2;
  float2* MLbuf = (float2*)(w + off); off += (size_t)nb * 8 * CH * 8;
  f16* Fqbuf = (f16*)(w + off);   off += (size_t)nb * 8 * CH * 2;
  f16* X16 = (f16*)(w + off);     off += (size_t)nb * SX * DDIM * 2;
  f16* Y16 = (f16*)(w + off);     off += (size_t)nb * SYY * DDIM * 2;
  f16* Yt16 = (f16*)(w + off);

  for (int b0 = 0; b0 < NBATCH; b0 += nb) {
    int nbc = (NBATCH - b0 < nb) ? (NBATCH - b0) : nb;
    k_prep_x<<<2048, 256, 0, stream>>>(
        (const float4*)(x + (size_t)b0 * SX * DDIM),
        out + (size_t)b0 * SX * 2 * DDIM, (h4_t*)X16,
        (long)nbc * SX * (DDIM / 4));
    dim3 tg(DDIM / 64, SYY / 64, nbc);
    k_trans<<<tg, 256, 0, stream>>>(y + (size_t)b0 * SYY * DDIM, Y16, Yt16);

    for (int i0 = 0; i0 < SX; i0 += CH) {
      int ntm = CH / 256;
      int nblk1 = nbc * ntm * (SYY / 256);
      int tpb = ((nblk1 & 15) == 0) ? 2 : 1;
      int nphys1 = nblk1 / tpb;
      k_gemm1<<<nphys1, 512, 0, stream>>>(X16, (long)SX * DDIM, i0, DDIM,
                                          Y16, (long)SYY * DDIM, DDIM,
                                          Ubuf, (long)CH * SYY,
                                          MLbuf, CH,
                                          DDIM, ntm, SYY / 256, nblk1, tpb);
      long rows_total = (long)nbc * CH;
      k_mlred<<<(unsigned)((rows_total + 255) / 256), 256, 0, stream>>>(
          MLbuf, Fqbuf, CH, rows_total);
      int nblk2 = nbc * ntm * (DDIM / 256);
      k_gemm2<<<nblk2, 512, 0, stream>>>(Ubuf, (long)CH * SYY, 0, SYY,
                                         Yt16, (long)DDIM * SYY, SYY,
                                         out + (size_t)b0 * SX * 2 * DDIM,
                                         (long)SX * 2 * DDIM, i0, 2 * DDIM, DDIM,
                                         Fqbuf, CH,
                                         SYY, ntm, DDIM / 256, nblk2);
    }
  }
}

// Round 8
// 231.318 us; speedup vs baseline: 1.0180x; 1.0180x over previous
//
#include <hip/hip_runtime.h>
#include <stdint.h>

#define SX 2048
#define SYY 2048
#define DDIM 1024
#define NBATCH 8

typedef _Float16 f16;
typedef __attribute__((ext_vector_type(2))) _Float16 h2_t;
typedef __attribute__((ext_vector_type(4))) _Float16 h4_t;
typedef __attribute__((ext_vector_type(8))) _Float16 h8_t;
typedef __attribute__((ext_vector_type(4))) float fx4_t;

__device__ __forceinline__ void gload_lds16(const void* g, void* l) {
  __builtin_amdgcn_global_load_lds((const __attribute__((address_space(1))) void*)g,
                                   (__attribute__((address_space(3))) void*)l,
                                   16, 0, 0);
}

// ---- prep: copy x into out[:, :, 0:D] (fp32) AND convert x -> fp16 ----
__global__ __launch_bounds__(256) void k_prep_x(const float4* __restrict__ x,
                                                float* __restrict__ out,
                                                h4_t* __restrict__ x16, long n4) {
  long i = (long)blockIdx.x * blockDim.x + threadIdx.x;
  long stride = (long)gridDim.x * blockDim.x;
  for (; i < n4; i += stride) {
    long bi = i >> 8;            // / (DDIM/4)
    int dq = (int)(i & 255);
    float4 v = x[i];
    *(float4*)(out + bi * (2 * DDIM) + dq * 4) = v;
    h4_t h = { (f16)v.x, (f16)v.y, (f16)v.z, (f16)v.w };
    x16[i] = h;
  }
}

// ---- y[z][j][d] fp32 -> Y16[z][j][d] fp16 and Yt16[z][d][j] fp16 ----
__global__ __launch_bounds__(256) void k_trans(const float* __restrict__ y,
                                               f16* __restrict__ y16,
                                               f16* __restrict__ yt16) {
  __shared__ f16 tile[64][72];
  int z = blockIdx.z;
  int d0 = blockIdx.x * 64, j0 = blockIdx.y * 64;
  const float* yb = y + (size_t)z * SYY * DDIM;
  f16* y16b = y16 + (size_t)z * SYY * DDIM;
  f16* ytb = yt16 + (size_t)z * DDIM * SYY;
  int t = threadIdx.x;
  int jl = t >> 2;
  int dq = t & 3;
#pragma unroll
  for (int s = 0; s < 4; ++s) {
    int dl = dq * 16 + s * 4;
    float4 v = *(const float4*)(yb + (size_t)(j0 + jl) * DDIM + d0 + dl);
    h4_t h = { (f16)v.x, (f16)v.y, (f16)v.z, (f16)v.w };
    *(h4_t*)(y16b + (size_t)(j0 + jl) * DDIM + d0 + dl) = h;
    *(h4_t*)&tile[jl][dl] = h;
  }
  __syncthreads();
  int dl2 = t >> 2;
  int jq = t & 3;
  f16 vbuf[16] __attribute__((aligned(16)));
#pragma unroll
  for (int u = 0; u < 16; ++u) vbuf[u] = tile[jq * 16 + u][dl2];
  f16* orow = ytb + (size_t)(d0 + dl2) * SYY + j0 + jq * 16;
  *(uint4*)orow = *(const uint4*)&vbuf[0];
  *(uint4*)(orow + 8) = *(const uint4*)&vbuf[8];
}

// ==== shared 256x256 8-phase GEMM machinery (round-3 verified ledger) ====
#define PH_BAR() __builtin_amdgcn_s_barrier()

#define STAGE_A(SLOT, HALF, T) {                                               \
    const f16* s_ = aRow + (size_t)((HALF) * 64) * lda + (T) * 64;             \
    f16* d_ = lds + (SLOT) * 8192 + dstoff;                                    \
    gload_lds16(s_, d_);                                                       \
    gload_lds16(s_ + (size_t)128 * lda, d_ + 4096); }

#define STAGE_B(SLOT, HALF, T) {                                               \
    const f16* s_ = bRow + (size_t)((HALF) * 32) * ldb + (T) * 64;             \
    f16* d_ = lds + (SLOT) * 8192 + dstoff;                                    \
    gload_lds16(s_, d_);                                                       \
    gload_lds16(s_ + (size_t)128 * ldb, d_ + 4096); }

#define RD_A(PTR, CB) { _Pragma("unroll") for (int i_ = 0; i_ < 4; ++i_) {     \
    af[i_][0] = *(const h8_t*)((PTR) + (CB) + i_ * 2048 + kb0);                \
    af[i_][1] = *(const h8_t*)((PTR) + (CB) + i_ * 2048 + kb1); } }

// gemm2 variant: scale A-fragments by per-row factor fdc[MOFF + i]
#define RD_A_S(PTR, CB, MOFF) { _Pragma("unroll") for (int i_ = 0; i_ < 4; ++i_) { \
    h8_t a0 = *(const h8_t*)((PTR) + (CB) + i_ * 2048 + kb0);                  \
    h8_t a1 = *(const h8_t*)((PTR) + (CB) + i_ * 2048 + kb1);                  \
    h2_t* p0 = (h2_t*)&a0; h2_t* p1 = (h2_t*)&a1;                              \
    _Pragma("unroll") for (int q_ = 0; q_ < 4; ++q_) {                         \
      p0[q_] *= fdc[(MOFF) + i_]; p1[q_] *= fdc[(MOFF) + i_]; }                \
    af[i_][0] = a0; af[i_][1] = a1; } }

#define RD_B(PTR, CB, NH) { _Pragma("unroll") for (int j_ = 0; j_ < 2; ++j_) { \
    bf[(NH) + j_][0] = *(const h8_t*)((PTR) + (CB) + j_ * 2048 + kb0);         \
    bf[(NH) + j_][1] = *(const h8_t*)((PTR) + (CB) + j_ * 2048 + kb1); } }

#define MM(MH, NH) { __builtin_amdgcn_s_setprio(1);                            \
  _Pragma("unroll") for (int i_ = 0; i_ < 4; ++i_)                             \
  _Pragma("unroll") for (int j_ = 0; j_ < 2; ++j_) {                           \
    acc[(MH) + i_][(NH) + j_] = __builtin_amdgcn_mfma_f32_16x16x32_f16(        \
        af[i_][0], bf[(NH) + j_][0], acc[(MH) + i_][(NH) + j_], 0, 0, 0);      \
    acc[(MH) + i_][(NH) + j_] = __builtin_amdgcn_mfma_f32_16x16x32_f16(        \
        af[i_][1], bf[(NH) + j_][1], acc[(MH) + i_][(NH) + j_], 0, 0, 0); }    \
  __builtin_amdgcn_s_setprio(0); }

// tile-id decode with XCD chunking + n-major half-m ordering for L2 reuse
#define DECODE_TILE()                                                          \
  int bid = blockIdx.x;                                                        \
  int id = bid;                                                                \
  if ((nblk & 7) == 0) { int cpx = nblk >> 3; id = (bid & 7) * cpx + (bid >> 3); } \
  int tpz = ntm * ntn;                                                         \
  int z = id / tpz;                                                            \
  int rem = id - z * tpz;                                                      \
  int mt, ntl;                                                                 \
  if ((ntm & 1) == 0) {                                                        \
    int ht = tpz >> 1, hm = ntm >> 1;                                          \
    int half = rem / ht, j = rem - half * ht;                                  \
    ntl = j / hm; mt = half * hm + (j - ntl * hm);                             \
  } else { mt = rem / ntn; ntl = rem - mt * ntn; }                             \
  int m0 = mt * 256, n0 = ntl * 256;

#define GEMM_COMMON_SETUP()                                                    \
  const int tid = threadIdx.x;                                                 \
  const int lane = tid & 63, w = tid >> 6;                                     \
  const int wr = w >> 2, wc = w & 3;                                           \
  const int fr = lane & 15, fh = lane >> 4;                                    \
  const f16* Ab = A + (size_t)z * a_zs + (size_t)(a_row0 + m0) * lda;          \
  const f16* Bb = B + (size_t)z * b_zs + (size_t)n0 * ldb;                     \
  const int l0 = 8 * w + (lane >> 3);                                          \
  const int r0a = l0;                                                          \
  const int r0b = ((l0 >> 5) << 6) | (l0 & 31);                                \
  const int swz = 8 * ((lane & 7) ^ (lane >> 3));                              \
  const f16* aRow = Ab + (size_t)r0a * lda + swz;                              \
  const f16* bRow = Bb + (size_t)r0b * ldb + swz;                              \
  const int dstoff = w * 512 + lane * 8;                                       \
  const char* ldsAlo = (const char*)lds + wr * 8192 + fr * 128;                \
  const char* ldsAhi = ldsAlo + 16384;                                         \
  const char* ldsBlo = (const char*)lds + 32768 + wc * 4096 + fr * 128;        \
  const char* ldsBhi = ldsBlo + 16384;                                         \
  const int kb0 = ((0 + fh) ^ (fr & 7)) * 16;                                  \
  const int kb1 = ((4 + fh) ^ (fr & 7)) * 16;

// ==== GEMM1: S = X16 . Y16^T, fused slim softmax epilogue + packed U store ====
__global__ __launch_bounds__(512, 2) void k_gemm1(
    const f16* __restrict__ A, long a_zs, int a_row0, int lda,
    const f16* __restrict__ B, long b_zs, int ldb,
    f16* __restrict__ U, long u_zs,
    float2* __restrict__ ML, int mrows,
    int K, int ntm, int ntn, int nblk)
{
  __shared__ f16 lds[65536];
  DECODE_TILE();
  GEMM_COMMON_SETUP();

  const int nt = K >> 6;
  const int ng = nt >> 1;

  fx4_t acc[8][4];
#pragma unroll
  for (int i = 0; i < 8; ++i)
#pragma unroll
    for (int j = 0; j < 4; ++j) { fx4_t zv = {0.f,0.f,0.f,0.f}; acc[i][j] = zv; }
  h8_t af[4][2], bf[4][2];

  STAGE_A(0, 0, 0); STAGE_A(1, 1, 0); STAGE_B(2, 0, 0); STAGE_B(3, 1, 0);
  STAGE_A(4, 0, 1); STAGE_B(6, 0, 1); STAGE_B(7, 1, 1);
  asm volatile("s_waitcnt vmcnt(6)" ::: "memory");
  PH_BAR();

  for (int g = 0; g < ng; ++g) {
    const int T1 = 2 * g + 1, T2 = 2 * g + 2, T3 = 2 * g + 3;
    const bool nl = (g < ng - 1);
    RD_A(ldsAlo, 0); RD_B(ldsBlo, 0, 0);
    STAGE_A(5, 1, T1);
    PH_BAR();
    MM(0, 0);
    PH_BAR();
    RD_B(ldsBhi, 0, 2);
    if (nl) STAGE_A(0, 0, T2);
    PH_BAR();
    MM(0, 2);
    PH_BAR();
    RD_A(ldsAhi, 0);
    if (nl) STAGE_B(2, 0, T2);
    PH_BAR();
    MM(4, 0);
    PH_BAR();
    if (nl) STAGE_B(3, 1, T2);
    PH_BAR();
    MM(4, 2);
    if (nl) { asm volatile("s_waitcnt vmcnt(6)" ::: "memory"); }
    else    { asm volatile("s_waitcnt vmcnt(0)" ::: "memory"); }
    PH_BAR();
    RD_A(ldsAlo, 65536); RD_B(ldsBlo, 65536, 0);
    if (nl) STAGE_A(1, 1, T2);
    PH_BAR();
    MM(0, 0);
    PH_BAR();
    RD_B(ldsBhi, 65536, 2);
    if (nl) STAGE_A(4, 0, T3);
    PH_BAR();
    MM(0, 2);
    PH_BAR();
    RD_A(ldsAhi, 65536);
    if (nl) STAGE_B(6, 0, T3);
    PH_BAR();
    MM(4, 0);
    PH_BAR();
    if (nl) STAGE_B(7, 1, T3);
    PH_BAR();
    MM(4, 2);
    asm volatile("s_waitcnt vmcnt(6)" ::: "memory");
    PH_BAR();
  }

  // ---- slim fused-softmax epilogue + LDS-packed coalesced U store ----
  __syncthreads();
  float2* mlx = (float2*)lds;                 // [256 rows][4 wc] float2 = 8KB
  const int rbase = wr * 128 + fh * 4;
  float mw[8][4];
#pragma unroll
  for (int mi = 0; mi < 8; ++mi)
#pragma unroll
    for (int rr = 0; rr < 4; ++rr) {
      float am = fmaxf(fmaxf(acc[mi][0][rr], acc[mi][1][rr]),
                       fmaxf(acc[mi][2][rr], acc[mi][3][rr]));
      am = fmaxf(am, __shfl_xor(am, 1)); am = fmaxf(am, __shfl_xor(am, 2));
      am = fmaxf(am, __shfl_xor(am, 4)); am = fmaxf(am, __shfl_xor(am, 8));
      float s = 0.f;
#pragma unroll
      for (int ni = 0; ni < 4; ++ni) {
        float e = __expf(acc[mi][ni][rr] - am);
        acc[mi][ni][rr] = e; s += e;
      }
      s += __shfl_xor(s, 1); s += __shfl_xor(s, 2);
      s += __shfl_xor(s, 4); s += __shfl_xor(s, 8);
      mw[mi][rr] = am;
      if (fr == 0) {
        float2 v; v.x = am; v.y = s;
        mlx[(rbase + mi * 16 + rr) * 4 + wc] = v;
      }
    }
  __syncthreads();
  float2* MLp = ML + ((size_t)z * 8 + (n0 >> 8)) * mrows + m0;
#pragma unroll
  for (int mi = 0; mi < 8; ++mi)
#pragma unroll
    for (int rr = 0; rr < 4; ++rr) {
      int row = rbase + mi * 16 + rr;
      float4 p01 = *(float4*)&mlx[row * 4 + 0];
      float4 p23 = *(float4*)&mlx[row * 4 + 2];
      float mt = fmaxf(fmaxf(p01.x, p01.z), fmaxf(p23.x, p23.z));
      float lt = p01.y * __expf(p01.x - mt) + p01.w * __expf(p01.z - mt) +
                 p23.y * __expf(p23.x - mt) + p23.w * __expf(p23.z - mt);
      if (wc == 0 && fr == 0) { float2 v; v.x = mt; v.y = lt; MLp[row] = v; }
      mw[mi][rr] = __expf(mw[mi][rr] - mt);     // sc = exp(am - mt)
    }
  __syncthreads();                              // mlx reads done; reuse LDS
  f16* wreg = lds + w * 8192;                   // per-wave [128][64] f16 = 16KB
#pragma unroll
  for (int mi = 0; mi < 8; ++mi)
#pragma unroll
    for (int ni = 0; ni < 4; ++ni)
#pragma unroll
      for (int rr = 0; rr < 4; ++rr)
        wreg[(mi * 16 + fh * 4 + rr) * 64 + ni * 16 + fr] =
            (f16)(acc[mi][ni][rr] * mw[mi][rr]);
  // coalesced store: lane covers rows i*8+(lane>>3), 16B chunk (lane&7)
  f16* Ub = U + (size_t)z * u_zs + (size_t)(m0 + wr * 128 + (lane >> 3)) * SYY +
            n0 + wc * 64 + (lane & 7) * 8;
  const f16* rsrc = wreg + (lane >> 3) * 64 + (lane & 7) * 8;
#pragma unroll
  for (int i = 0; i < 16; ++i)
    *(uint4*)(Ub + (size_t)(i * 8) * SYY) = *(const uint4*)(rsrc + i * 512);
}

// ---- per-row combine: 8 tiles' (m,l) -> factor_t = exp(m_t - M)/L (f16) ----
__global__ __launch_bounds__(256) void k_mlred(const float2* __restrict__ ML,
                                               f16* __restrict__ Fq,
                                               int rows, long total) {
  long idx = (long)blockIdx.x * blockDim.x + threadIdx.x;
  if (idx >= total) return;
  int z = (int)(idx / rows);
  int r = (int)(idx - (long)z * rows);
  float2 v[8];
  float M = -3.4e38f;
#pragma unroll
  for (int t = 0; t < 8; ++t) {
    v[t] = ML[((size_t)z * 8 + t) * rows + r];
    M = fmaxf(M, v[t].x);
  }
  float L = 0.f;
#pragma unroll
  for (int t = 0; t < 8; ++t) L += v[t].y * __expf(v[t].x - M);
  float inv = 1.0f / L;
#pragma unroll
  for (int t = 0; t < 8; ++t)
    Fq[((size_t)z * 8 + t) * rows + r] = (f16)(__expf(v[t].x - M) * inv);
}

// ==== GEMM2: out_right = (u * factor) . Yt^T, factor applied on A-frags ====
__global__ __launch_bounds__(512, 2) void k_gemm2(
    const f16* __restrict__ A, long a_zs, int a_row0, int lda,
    const f16* __restrict__ B, long b_zs, int ldb,
    float* __restrict__ C, long c_zs, int c_row0, int ldc, int c_col0,
    const f16* __restrict__ Fq, int mrows,
    int K, int ntm, int ntn, int nblk)
{
  __shared__ f16 lds[65536];
  DECODE_TILE();
  GEMM_COMMON_SETUP();

  const int nt = K >> 6;
  const int ng = nt >> 1;

  fx4_t acc[8][4];
#pragma unroll
  for (int i = 0; i < 8; ++i)
#pragma unroll
    for (int j = 0; j < 4; ++j) { fx4_t zv = {0.f,0.f,0.f,0.f}; acc[i][j] = zv; }
  h8_t af[4][2], bf[4][2];

  // factor base: row(mi) = m0 + wr*128 + mi*16 + fr, table [z][t][mrows]
  const f16* Fb = Fq + (size_t)z * 8 * mrows + m0 + wr * 128 + fr;
  h2_t fdc[8], fdn[8];
#pragma unroll
  for (int i = 0; i < 8; ++i) {
    f16 fv = Fb[i * 16];
    h2_t d; d[0] = fv; d[1] = fv; fdn[i] = d;
  }

  STAGE_A(0, 0, 0); STAGE_A(1, 1, 0); STAGE_B(2, 0, 0); STAGE_B(3, 1, 0);
  STAGE_A(4, 0, 1); STAGE_B(6, 0, 1); STAGE_B(7, 1, 1);
  asm volatile("s_waitcnt vmcnt(6)" ::: "memory");
  PH_BAR();

  for (int g = 0; g < ng; ++g) {
    const int T1 = 2 * g + 1, T2 = 2 * g + 2, T3 = 2 * g + 3;
    const bool nl = (g < ng - 1);
    const bool ev = ((g & 1) == 0);
    if (ev) {
#pragma unroll
      for (int i = 0; i < 8; ++i) fdc[i] = fdn[i];
    }
    RD_A_S(ldsAlo, 0, 0); RD_B(ldsBlo, 0, 0);
    STAGE_A(5, 1, T1);
    PH_BAR(); MM(0, 0); PH_BAR();
    RD_B(ldsBhi, 0, 2);
    if (nl) STAGE_A(0, 0, T2);
    PH_BAR(); MM(0, 2); PH_BAR();
    RD_A_S(ldsAhi, 0, 4);
    if (nl) STAGE_B(2, 0, T2);
    PH_BAR(); MM(4, 0); PH_BAR();
    if (nl) STAGE_B(3, 1, T2);
    PH_BAR(); MM(4, 2);
    if (nl) { asm volatile("s_waitcnt vmcnt(6)" ::: "memory"); }
    else    { asm volatile("s_waitcnt vmcnt(0)" ::: "memory"); }
    PH_BAR();
    // ph4: factor prefetch AFTER the checkpoint (keeps stage FIFO ledger exact)
    RD_A_S(ldsAlo, 65536, 0); RD_B(ldsBlo, 65536, 0);
    if (ev) {
      int tn = (g >> 1) + 1;
      if (tn < 8) {
        const f16* Fn = Fb + (size_t)tn * mrows;
#pragma unroll
        for (int i = 0; i < 8; ++i) {
          f16 fv = Fn[i * 16];
          h2_t d; d[0] = fv; d[1] = fv; fdn[i] = d;
        }
      }
    }
    if (nl) STAGE_A(1, 1, T2);
    PH_BAR(); MM(0, 0); PH_BAR();
    RD_B(ldsBhi, 65536, 2);
    if (nl) STAGE_A(4, 0, T3);
    PH_BAR(); MM(0, 2); PH_BAR();
    RD_A_S(ldsAhi, 65536, 4);
    if (nl) STAGE_B(6, 0, T3);
    PH_BAR(); MM(4, 0); PH_BAR();
    if (nl) STAGE_B(7, 1, T3);
    PH_BAR(); MM(4, 2);
    asm volatile("s_waitcnt vmcnt(6)" ::: "memory");
    PH_BAR();
  }

  float* Cb = C + (size_t)z * c_zs +
              (size_t)(c_row0 + m0 + wr * 128) * ldc + c_col0 + n0 + wc * 64;
#pragma unroll
  for (int mi = 0; mi < 8; ++mi)
#pragma unroll
    for (int ni = 0; ni < 4; ++ni)
#pragma unroll
      for (int r = 0; r < 4; ++r)
        Cb[(size_t)(mi * 16 + fh * 4 + r) * ldc + ni * 16 + fr] = acc[mi][ni][r];
}

extern "C" void kernel_launch(void* const* d_in, const int* in_sizes, int n_in,
                              void* d_out, int out_size, void* d_ws, size_t ws_size,
                              hipStream_t stream) {
  (void)in_sizes; (void)n_in; (void)out_size;
  const float* x = (const float*)d_in[0];
  const float* y = (const float*)d_in[1];
  float* out = (float*)d_out;

  // ws layout per group: U(f16) | ML(float2 x8) | Fq(f16 x8) | X16 | Y16 | Yt16
  size_t per_batch = (size_t)SX * SYY * 2 + (size_t)8 * SX * 8 + (size_t)8 * SX * 2 +
                     (size_t)SX * DDIM * 2 + (size_t)SYY * DDIM * 2 +
                     (size_t)DDIM * SYY * 2;
  int nb = (int)(ws_size / per_batch);
  if (nb > NBATCH) nb = NBATCH;
  int CH = SX;
  if (nb < 1) {
    nb = 1;
    size_t conv = (size_t)SX * DDIM * 2 + (size_t)SYY * DDIM * 2 +
                  (size_t)DDIM * SYY * 2;
    size_t avail = ws_size > conv ? ws_size - conv : 0;
    long ch = (long)(avail / ((size_t)SYY * 2 + 80));
    ch = (ch / 256) * 256;
    if (ch < 256) ch = 256;
    if (ch > SX) ch = SX;
    CH = (int)ch;
  }

  char* w = (char*)d_ws;
  f16* Ubuf = (f16*)w;            size_t off = (size_t)nb * CH * SYY * 2;
  float2* MLbuf = (float2*)(w + off); off += (size_t)nb * 8 * CH * 8;
  f16* Fqbuf = (f16*)(w + off);   off += (size_t)nb * 8 * CH * 2;
  f16* X16 = (f16*)(w + off);     off += (size_t)nb * SX * DDIM * 2;
  f16* Y16 = (f16*)(w + off);     off += (size_t)nb * SYY * DDIM * 2;
  f16* Yt16 = (f16*)(w + off);

  for (int b0 = 0; b0 < NBATCH; b0 += nb) {
    int nbc = (NBATCH - b0 < nb) ? (NBATCH - b0) : nb;
    k_prep_x<<<2048, 256, 0, stream>>>(
        (const float4*)(x + (size_t)b0 * SX * DDIM),
        out + (size_t)b0 * SX * 2 * DDIM, (h4_t*)X16,
        (long)nbc * SX * (DDIM / 4));
    dim3 tg(DDIM / 64, SYY / 64, nbc);
    k_trans<<<tg, 256, 0, stream>>>(y + (size_t)b0 * SYY * DDIM, Y16, Yt16);

    for (int i0 = 0; i0 < SX; i0 += CH) {
      int ntm = CH / 256;
      int nblk1 = nbc * ntm * (SYY / 256);
      k_gemm1<<<nblk1, 512, 0, stream>>>(X16, (long)SX * DDIM, i0, DDIM,
                                         Y16, (long)SYY * DDIM, DDIM,
                                         Ubuf, (long)CH * SYY,
                                         MLbuf, CH,
                                         DDIM, ntm, SYY / 256, nblk1);
      long rows_total = (long)nbc * CH;
      k_mlred<<<(unsigned)((rows_total + 255) / 256), 256, 0, stream>>>(
          MLbuf, Fqbuf, CH, rows_total);
      int nblk2 = nbc * ntm * (DDIM / 256);
      k_gemm2<<<nblk2, 512, 0, stream>>>(Ubuf, (long)CH * SYY, 0, SYY,
                                         Yt16, (long)DDIM * SYY, SYY,
                                         out + (size_t)b0 * SX * 2 * DDIM,
                                         (long)SX * 2 * DDIM, i0, 2 * DDIM, DDIM,
                                         Fqbuf, CH,
                                         SYY, ntm, DDIM / 256, nblk2);
    }
  }
}